// Round 16
// baseline (203.829 us; speedup 1.0000x reference)
//
#include <hip/hip_runtime.h>
#include <stdint.h>
#include <stddef.h>

// BERT encoder layer, MI355X. Round 16:
// - attention QBLK=128: 4 waves x 32 q-rows, each wave covers ALL tile keys
//   (no key-split, merge phase deleted); per-q staging/barrier/L2 cost halved.
//   Inner body = round-15's verified kh-body looped over both 64-key halves.
#define HD 768
#define FF 3072
#define NHEAD 12
#define DHEAD 64
#define SEQ 2048
#define BATCH 2
#define NTOK (SEQ*BATCH)   // 4096
#define SM_SCALE 0.18033688f   // log2(e)/8

typedef __attribute__((ext_vector_type(8))) __bf16 bf16x8;
typedef __attribute__((ext_vector_type(4))) float f32x4;

__device__ __forceinline__ unsigned short f2bf(float f) {
  unsigned int u = __builtin_bit_cast(unsigned int, f);
  u += 0x7fffu + ((u >> 16) & 1u);
  return (unsigned short)(u >> 16);
}
__device__ __forceinline__ float bf2f(unsigned int s) {
  unsigned int u = s << 16;
  return __builtin_bit_cast(float, u);
}
__device__ __forceinline__ float4 ld4bf(const unsigned short* p) {
  uint2 w = *reinterpret_cast<const uint2*>(p);
  float4 o;
  o.x = bf2f(w.x & 0xffffu); o.y = bf2f(w.x >> 16);
  o.z = bf2f(w.y & 0xffffu); o.w = bf2f(w.y >> 16);
  return o;
}

// async global->LDS, 16B per lane; LDS dest = uniform base + lane*16
__device__ __forceinline__ void gl16(const unsigned short* g, unsigned short* l) {
  __builtin_amdgcn_global_load_lds(
      (const __attribute__((address_space(1))) void*)g,
      (__attribute__((address_space(3))) void*)l,
      16, 0, 0);
}

// ---------------- prep kernel (weight transposes + x cvt + bias concat) ----------------
__global__ void k_prep(const float* __restrict__ Wq, const float* __restrict__ Wk,
                       const float* __restrict__ Wv, const float* __restrict__ Wa1,
                       const float* __restrict__ W1, const float* __restrict__ W2,
                       const float* __restrict__ Wa2,
                       unsigned short* __restrict__ WqkvT, unsigned short* __restrict__ Wa1T,
                       unsigned short* __restrict__ W1T, unsigned short* __restrict__ W2T,
                       unsigned short* __restrict__ Wa2T,
                       const float* __restrict__ x, unsigned short* __restrict__ xb, int n4,
                       const float* __restrict__ bq, const float* __restrict__ bk,
                       const float* __restrict__ bv, float* __restrict__ biasqkv) {
  int t = blockIdx.x;
  int tid = threadIdx.x;
  if (t >= 7488) {
    int tb = t - 7488;
    if (tb < 9) {
      int idx = tb * 256 + tid;
      if (idx < 3*HD) {
        float v = idx < HD ? bq[idx] : idx < 2*HD ? bk[idx-HD] : bv[idx-2*HD];
        biasqkv[idx] = v;
      }
    }
    int i = tb * 256 + tid;
    int stride = 2048 * 256;
    for (; i < n4; i += stride) {
      float4 v = reinterpret_cast<const float4*>(x)[i];
      ushort4 o;
      o.x = f2bf(v.x); o.y = f2bf(v.y); o.z = f2bf(v.z); o.w = f2bf(v.w);
      reinterpret_cast<ushort4*>(xb)[i] = o;
    }
    return;
  }
  __shared__ float tile[32][33];
  const float* in; unsigned short* out; int K, N;
  if (t < 2304)      { int seg = t / 576; t -= seg * 576; K = HD; N = HD;
                       in  = seg==0 ? Wq : seg==1 ? Wk : seg==2 ? Wv : Wa1;
                       out = seg<3 ? WqkvT + seg*HD*HD : Wa1T; }
  else if (t < 4608) { t -= 2304; in = W1;  out = W1T;  K = HD; N = FF; }
  else if (t < 6912) { t -= 4608; in = W2;  out = W2T;  K = FF; N = HD; }
  else               { t -= 6912; in = Wa2; out = Wa2T; K = HD; N = HD; }
  int nt = N / 32;
  int nb = (t % nt) * 32, kb = (t / nt) * 32;
  int tx = tid & 31, ty = tid >> 5;   // 32 x 8
  for (int i = ty; i < 32; i += 8)
    tile[i][tx] = in[(size_t)(kb + i) * N + nb + tx];
  __syncthreads();
  for (int i = ty; i < 32; i += 8)
    out[(size_t)(nb + i) * K + kb + tx] = f2bf(tile[tx][i]);
}

// ---------------- GEMM (BK=64, XOR-chunk swizzle, XCD-swizzled grid) ----------------
// MODE 1: bf16 out; 2: tanh-GELU->bf16; 3: QKV (Q cols * SM_SCALE, V cols -> Vout transposed)

#define BN 128
#define BK 64

template<int MODE, int TBM>
__global__ __launch_bounds__(256, 3)
void k_gemm(const unsigned short* __restrict__ A, const unsigned short* __restrict__ Bt,
            const float* __restrict__ bias, void* __restrict__ Cout,
            unsigned short* __restrict__ Vout,
            int M, int N, int K) {
  constexpr int MR = TBM / 32;
  constexpr int AI = TBM / 32;
  __shared__ unsigned short As[TBM*BK];
  __shared__ unsigned short Bs[BN*BK];
  int tid = threadIdx.x;
  int nwg = gridDim.x * gridDim.y;
  int lin = blockIdx.x + gridDim.x * blockIdx.y;
  int nl = (lin & 7) * (nwg >> 3) + (lin >> 3);
  int bm = (nl % gridDim.x) * TBM;
  int bn = (nl / gridDim.x) * BN;
  int wave = tid >> 6, lane = tid & 63;
  int wm = wave >> 1, wn = wave & 1;
  int wr = wm * (TBM/2);
  int wc = wn * 64;
  int fr = lane & 15;
  int hi = lane >> 4;

  f32x4 acc[MR][4];
#pragma unroll
  for (int m = 0; m < MR; ++m)
#pragma unroll
    for (int n = 0; n < 4; ++n) acc[m][n] = (f32x4){0.f,0.f,0.f,0.f};

  int g8 = lane >> 3;
  int cc = (lane & 7) ^ g8;
  int arow = (TBM/4)*wave + g8;
  int brow = 32*wave + g8;
  const unsigned short* ag = A + (size_t)(bm + arow) * K + cc*8;
  const unsigned short* bg = Bt + (size_t)(bn + brow) * K + cc*8;
  unsigned short* asl = As + (TBM/4)*wave*BK;
  unsigned short* bsl = Bs + 32*wave*BK;

  for (int k0 = 0; k0 < K; k0 += BK) {
#pragma unroll
    for (int i = 0; i < AI; ++i)
      gl16(ag + (size_t)(8*i)*K + k0, asl + (8*i)*BK);
#pragma unroll
    for (int i = 0; i < 4; ++i)
      gl16(bg + (size_t)(8*i)*K + k0, bsl + (8*i)*BK);
    __syncthreads();

    bf16x8 af[MR][2], bf[4][2];
#pragma unroll
    for (int m = 0; m < MR; ++m) {
      int R = wr + m*16 + fr, sw = R & 7;
#pragma unroll
      for (int h2 = 0; h2 < 2; ++h2)
        af[m][h2] = __builtin_bit_cast(bf16x8,
          *reinterpret_cast<const uint4*>(&As[R*BK + ((hi + h2*4) ^ sw)*8]));
    }
#pragma unroll
    for (int n = 0; n < 4; ++n) {
      int R = wc + n*16 + fr, sw = R & 7;
#pragma unroll
      for (int h2 = 0; h2 < 2; ++h2)
        bf[n][h2] = __builtin_bit_cast(bf16x8,
          *reinterpret_cast<const uint4*>(&Bs[R*BK + ((hi + h2*4) ^ sw)*8]));
    }
#pragma unroll
    for (int m = 0; m < MR; ++m)
#pragma unroll
      for (int n = 0; n < 4; ++n) {
        acc[m][n] = __builtin_amdgcn_mfma_f32_16x16x32_bf16(af[m][0], bf[n][0], acc[m][n], 0, 0, 0);
        acc[m][n] = __builtin_amdgcn_mfma_f32_16x16x32_bf16(af[m][1], bf[n][1], acc[m][n], 0, 0, 0);
      }
    __syncthreads();
  }

  int crow0 = (lane >> 4) * 4;
  int ccol = lane & 15;

  if (MODE == 3 && bn >= 2*HD) {
    unsigned short* tb = (wave < 2) ? As + wave*4096 : Bs + (wave-2)*4096;
#pragma unroll
    for (int m = 0; m < MR; ++m)
#pragma unroll
      for (int n = 0; n < 4; ++n)
#pragma unroll
        for (int r = 0; r < 4; ++r) {
          int tl = m*16 + crow0 + r;
          int cl = n*16 + ccol;
          float v = acc[m][n][r] + bias[bn + wc + cl];
          int pt = ((tl>>2)&3)*16 + ((tl>>4)<<2) + (tl&3);
          tb[cl*64 + (((pt>>3) ^ (cl&7))<<3) + (pt&7)] = f2bf(v);
        }
    __syncthreads();
    int tk0 = bm + wr;
    int bb = tk0 >> 11;
    int sb = tk0 & 2047;
    int hh = (bn + wc - 2*HD) >> 6;
    unsigned short* dst = Vout + ((size_t)(bb*NHEAD + hh) * DHEAD) * SEQ + sb;
#pragma unroll
    for (int p = 0; p < 8; ++p) {
      int dr = p*8 + (lane >> 3);
      int cj = lane & 7;
      uint4 w = *reinterpret_cast<const uint4*>(&tb[dr*64 + ((cj ^ (dr&7))<<3)]);
      *reinterpret_cast<uint4*>(dst + (size_t)dr*SEQ + cj*8) = w;
    }
    return;
  }

#pragma unroll
  for (int m = 0; m < MR; ++m) {
#pragma unroll
    for (int n = 0; n < 4; ++n) {
      int gcol = bn + wc + n*16 + ccol;
      float bv_ = bias[gcol];
#pragma unroll
      for (int r = 0; r < 4; ++r) {
        int grow = bm + wr + m*16 + crow0 + r;
        float v = acc[m][n][r] + bv_;
        if (MODE == 2) {
          float a = v + 0.044715f * v * v * v;
          v = v / (1.0f + exp2f(-2.3022082f * a));
        }
        if (MODE == 3 && gcol < HD) v *= SM_SCALE;
        reinterpret_cast<unsigned short*>(Cout)[(size_t)grow * N + gcol] = f2bf(v);
      }
    }
  }
}

// ---------------- MFMA flash attention (QBLK=128, KVB=128, no key-split) ----------------
// Block = 128 q-rows, 4 waves; wave w owns q-rows [w*32, +32) (frags A/B),
// covers ALL 128 keys of each tile (hh = 0,1 inner halves). Denominator via
// MFMA against ones-row (Vt rows 64..79). No merge phase.

#define KVB 128
#define KPK 72    // K pitch (shorts)
#define KPV 136   // V pitch (shorts)

__global__ __launch_bounds__(256, 3)
void k_attn_mfma(const unsigned short* __restrict__ qkv,
                 const unsigned short* __restrict__ vt,
                 unsigned short* __restrict__ ctx) {
  __shared__ __align__(16) char smem[40192];
  auto Ks = reinterpret_cast<unsigned short(*)[KPK]>(smem);            // [128][72]  = 18432 B
  auto Vt = reinterpret_cast<unsigned short(*)[KPV]>(smem + 18432);    // [80][136]  = 21760 B

  int tid = threadIdx.x;
  int wv = tid >> 6, lane = tid & 63;
  int lo = lane & 15, hi = lane >> 4;

  // XCD swizzle: bijective remap of 384 blocks (384 = 8*48)
  int lin = blockIdx.x + 16*(blockIdx.y + NHEAD*blockIdx.z);
  int nl = (lin & 7) * 48 + (lin >> 3);
  int qb = nl & 15;
  int rest = nl >> 4;
  int h = rest % NHEAD;
  int b = rest / NHEAD;
  int q0 = qb * 128;

  // ones/zero rows for the denominator MFMA (written once; staging rows < 64)
  for (int idx = tid; idx < 16*KPV; idx += 256) {
    int rr = idx / KPV, cc2 = idx - rr*KPV;
    Vt[64 + rr][cc2] = (rr == 0) ? (unsigned short)0x3F80 : (unsigned short)0;
  }

  const unsigned short* qpA = qkv + (size_t)(b*SEQ + q0 + wv*32 + lo) * 2304 + h*DHEAD + hi*8;
  const unsigned short* qpB = qpA + (size_t)16 * 2304;
  bf16x8 qfA0 = __builtin_bit_cast(bf16x8, *reinterpret_cast<const uint4*>(qpA));
  bf16x8 qfA1 = __builtin_bit_cast(bf16x8, *reinterpret_cast<const uint4*>(qpA + 32));
  bf16x8 qfB0 = __builtin_bit_cast(bf16x8, *reinterpret_cast<const uint4*>(qpB));
  bf16x8 qfB1 = __builtin_bit_cast(bf16x8, *reinterpret_cast<const uint4*>(qpB + 32));

  f32x4 poA[4], poB[4], po5A, po5B;
#pragma unroll
  for (int dt = 0; dt < 4; ++dt) { poA[dt] = (f32x4){0.f,0.f,0.f,0.f}; poB[dt] = (f32x4){0.f,0.f,0.f,0.f}; }
  po5A = (f32x4){0.f,0.f,0.f,0.f};
  po5B = (f32x4){0.f,0.f,0.f,0.f};

  // staging: K 128 rows x 64 shorts (2 threads/row), V 64 rows x 128 shorts (4 threads/row)
  int ksr = tid >> 1, kc = (tid & 1) * 32;
  int vdr = tid >> 2, vc = (tid & 3) * 32;
  const unsigned short* kgl = qkv + (size_t)(b*SEQ)*2304 + HD + h*DHEAD;
  const unsigned short* vgl = vt + ((size_t)(b*NHEAD + h)) * DHEAD * SEQ;

  for (int t0 = 0; t0 < SEQ; t0 += KVB) {
    const unsigned short* kp = kgl + (size_t)(t0 + ksr)*2304 + kc;
    const unsigned short* vp = vgl + (size_t)vdr*SEQ + t0 + vc;
    uint4 ku0 = *reinterpret_cast<const uint4*>(kp);
    uint4 ku1 = *reinterpret_cast<const uint4*>(kp + 8);
    uint4 ku2 = *reinterpret_cast<const uint4*>(kp + 16);
    uint4 ku3 = *reinterpret_cast<const uint4*>(kp + 24);
    uint4 vu0 = *reinterpret_cast<const uint4*>(vp);
    uint4 vu1 = *reinterpret_cast<const uint4*>(vp + 8);
    uint4 vu2 = *reinterpret_cast<const uint4*>(vp + 16);
    uint4 vu3 = *reinterpret_cast<const uint4*>(vp + 24);
    __syncthreads();
    *reinterpret_cast<uint4*>(&Ks[ksr][kc])      = ku0;
    *reinterpret_cast<uint4*>(&Ks[ksr][kc + 8])  = ku1;
    *reinterpret_cast<uint4*>(&Ks[ksr][kc + 16]) = ku2;
    *reinterpret_cast<uint4*>(&Ks[ksr][kc + 24]) = ku3;
    *reinterpret_cast<uint4*>(&Vt[vdr][vc])      = vu0;
    *reinterpret_cast<uint4*>(&Vt[vdr][vc + 8])  = vu1;
    *reinterpret_cast<uint4*>(&Vt[vdr][vc + 16]) = vu2;
    *reinterpret_cast<uint4*>(&Vt[vdr][vc + 24]) = vu3;
    __syncthreads();

#pragma unroll
    for (int hh = 0; hh < 2; ++hh) {
      // QK^T: keys hh*64 + kg*16 + hi*4 + r
      f32x4 sA[4], sB[4];
#pragma unroll
      for (int kg = 0; kg < 4; ++kg) {
        int krow = hh*64 + kg*16 + lo;
        bf16x8 a0 = __builtin_bit_cast(bf16x8, *reinterpret_cast<const uint4*>(&Ks[krow][hi*8]));
        bf16x8 a1 = __builtin_bit_cast(bf16x8, *reinterpret_cast<const uint4*>(&Ks[krow][32 + hi*8]));
        f32x4 s = (f32x4){0.f,0.f,0.f,0.f};
        s = __builtin_amdgcn_mfma_f32_16x16x32_bf16(a0, qfA0, s, 0, 0, 0);
        s = __builtin_amdgcn_mfma_f32_16x16x32_bf16(a1, qfA1, s, 0, 0, 0);
        sA[kg] = s;
        s = (f32x4){0.f,0.f,0.f,0.f};
        s = __builtin_amdgcn_mfma_f32_16x16x32_bf16(a0, qfB0, s, 0, 0, 0);
        s = __builtin_amdgcn_mfma_f32_16x16x32_bf16(a1, qfB1, s, 0, 0, 0);
        sB[kg] = s;
      }

      // no-max softmax + cvt_pk packing
      unsigned int pwA[8], pwB[8];
#pragma unroll
      for (int kg = 0; kg < 4; ++kg) {
        float a0 = exp2f(sA[kg][0]), a1 = exp2f(sA[kg][1]);
        float a2 = exp2f(sA[kg][2]), a3 = exp2f(sA[kg][3]);
        asm("v_cvt_pk_bf16_f32 %0, %1, %2" : "=v"(pwA[kg*2])   : "v"(a0), "v"(a1));
        asm("v_cvt_pk_bf16_f32 %0, %1, %2" : "=v"(pwA[kg*2+1]) : "v"(a2), "v"(a3));
        float b0 = exp2f(sB[kg][0]), b1 = exp2f(sB[kg][1]);
        float b2 = exp2f(sB[kg][2]), b3 = exp2f(sB[kg][3]);
        asm("v_cvt_pk_bf16_f32 %0, %1, %2" : "=v"(pwB[kg*2])   : "v"(b0), "v"(b1));
        asm("v_cvt_pk_bf16_f32 %0, %1, %2" : "=v"(pwB[kg*2+1]) : "v"(b2), "v"(b3));
      }

      uint4 uA0; uA0.x = pwA[0]; uA0.y = pwA[1]; uA0.z = pwA[2]; uA0.w = pwA[3];
      uint4 uA1; uA1.x = pwA[4]; uA1.y = pwA[5]; uA1.z = pwA[6]; uA1.w = pwA[7];
      uint4 uB0; uB0.x = pwB[0]; uB0.y = pwB[1]; uB0.z = pwB[2]; uB0.w = pwB[3];
      uint4 uB1; uB1.x = pwB[4]; uB1.y = pwB[5]; uB1.z = pwB[6]; uB1.w = pwB[7];
      bf16x8 paA0 = __builtin_bit_cast(bf16x8, uA0);
      bf16x8 paA1 = __builtin_bit_cast(bf16x8, uA1);
      bf16x8 paB0 = __builtin_bit_cast(bf16x8, uB0);
      bf16x8 paB1 = __builtin_bit_cast(bf16x8, uB1);

      // PV (keys hh*64.., permuted storage): slots hi*16+j / +8
#pragma unroll
      for (int dt = 0; dt < 4; ++dt) {
        int col = dt*16 + lo;
        bf16x8 v0 = __builtin_bit_cast(bf16x8, *reinterpret_cast<const uint4*>(&Vt[col][hh*64 + hi*16]));
        bf16x8 v1 = __builtin_bit_cast(bf16x8, *reinterpret_cast<const uint4*>(&Vt[col][hh*64 + hi*16 + 8]));
        poA[dt] = __builtin_amdgcn_mfma_f32_16x16x32_bf16(paA0, v0, poA[dt], 0, 0, 0);
        poA[dt] = __builtin_amdgcn_mfma_f32_16x16x32_bf16(paA1, v1, poA[dt], 0, 0, 0);
        poB[dt] = __builtin_amdgcn_mfma_f32_16x16x32_bf16(paB0, v0, poB[dt], 0, 0, 0);
        poB[dt] = __builtin_amdgcn_mfma_f32_16x16x32_bf16(paB1, v1, poB[dt], 0, 0, 0);
      }
      // denominator: ones-row block (rows 64..79)
      {
        bf16x8 o0 = __builtin_bit_cast(bf16x8, *reinterpret_cast<const uint4*>(&Vt[64 + lo][hh*64 + hi*16]));
        bf16x8 o1 = __builtin_bit_cast(bf16x8, *reinterpret_cast<const uint4*>(&Vt[64 + lo][hh*64 + hi*16 + 8]));
        po5A = __builtin_amdgcn_mfma_f32_16x16x32_bf16(paA0, o0, po5A, 0, 0, 0);
        po5A = __builtin_amdgcn_mfma_f32_16x16x32_bf16(paA1, o1, po5A, 0, 0, 0);
        po5B = __builtin_amdgcn_mfma_f32_16x16x32_bf16(paB0, o0, po5B, 0, 0, 0);
        po5B = __builtin_amdgcn_mfma_f32_16x16x32_bf16(paB1, o1, po5B, 0, 0, 0);
      }
    }
  }

  // epilogue: denominator for row hi*4+r lives on lane hi*16, register r
  unsigned short* op = ctx + (size_t)(b*SEQ + q0 + wv*32) * HD + h*DHEAD;
#pragma unroll
  for (int r = 0; r < 4; ++r) {
    float LA = __shfl(po5A[r], hi*16);
    float LB = __shfl(po5B[r], hi*16);
    float liA = (LA > 0.f) ? 1.0f / LA : 0.f;
    float liB = (LB > 0.f) ? 1.0f / LB : 0.f;
    int row = hi*4 + r;
#pragma unroll
    for (int dt = 0; dt < 4; ++dt) {
      op[(size_t)row*HD + dt*16 + lo]        = f2bf(poA[dt][r] * liA);
      op[(size_t)(16 + row)*HD + dt*16 + lo] = f2bf(poB[dt][r] * liB);
    }
  }
}

// ---------------- LayerNorm (bf16 input) ----------------
template<int RESID_BF16, int WRITE_F32>
__global__ __launch_bounds__(256, 4)
void k_ln(const unsigned short* __restrict__ xin, const void* __restrict__ resid_,
          const float* __restrict__ g, const float* __restrict__ be,
          float* __restrict__ outf, unsigned short* __restrict__ outb) {
  int wave = threadIdx.x >> 6, lane = threadIdx.x & 63;
  int row = blockIdx.x * 4 + wave;
  const unsigned short* xp = xin + (size_t)row * HD;
  const float4* gp = reinterpret_cast<const float4*>(g);
  const float4* bp = reinterpret_cast<const float4*>(be);
  float4 v[3];
  float sum = 0.f, sq = 0.f;
#pragma unroll
  for (int i = 0; i < 3; ++i) {
    v[i] = ld4bf(xp + (lane + 64*i)*4);
    sum += v[i].x + v[i].y + v[i].z + v[i].w;
    sq  += v[i].x*v[i].x + v[i].y*v[i].y + v[i].z*v[i].z + v[i].w*v[i].w;
  }
#pragma unroll
  for (int m = 1; m < 64; m <<= 1) { sum += __shfl_xor(sum, m); sq += __shfl_xor(sq, m); }
  float mean = sum * (1.0f/768.0f);
  float var = sq * (1.0f/768.0f) - mean*mean;
  float rstd = rsqrtf(var + 1e-5f);
#pragma unroll
  for (int i = 0; i < 3; ++i) {
    float4 gg = gp[lane + 64*i], bb = bp[lane + 64*i];
    float4 rr;
    if (RESID_BF16)
      rr = ld4bf((const unsigned short*)resid_ + (size_t)row * HD + (lane + 64*i)*4);
    else
      rr = reinterpret_cast<const float4*>((const float*)resid_ + (size_t)row * HD)[lane + 64*i];
    float4 o;
    o.x = (v[i].x - mean)*rstd*gg.x + bb.x + rr.x;
    o.y = (v[i].y - mean)*rstd*gg.y + bb.y + rr.y;
    o.z = (v[i].z - mean)*rstd*gg.z + bb.z + rr.z;
    o.w = (v[i].w - mean)*rstd*gg.w + bb.w + rr.w;
    if (WRITE_F32) {
      reinterpret_cast<float4*>(outf + (size_t)row * HD)[lane + 64*i] = o;
    } else {
      ushort4 ob;
      ob.x = f2bf(o.x); ob.y = f2bf(o.y); ob.z = f2bf(o.z); ob.w = f2bf(o.w);
      reinterpret_cast<ushort4*>(outb + (size_t)row * HD)[lane + 64*i] = ob;
    }
  }
}

// ---------------- launch ----------------

extern "C" void kernel_launch(void* const* d_in, const int* in_sizes, int n_in,
                              void* d_out, int out_size, void* d_ws, size_t ws_size,
                              hipStream_t stream) {
  const float* x   = (const float*)d_in[0];
  const float* Wq  = (const float*)d_in[1];
  const float* bq  = (const float*)d_in[2];
  const float* Wk  = (const float*)d_in[3];
  const float* bk  = (const float*)d_in[4];
  const float* Wv  = (const float*)d_in[5];
  const float* bv  = (const float*)d_in[6];
  const float* Wa1 = (const float*)d_in[7];
  const float* ba1 = (const float*)d_in[8];
  const float* g1  = (const float*)d_in[9];
  const float* be1 = (const float*)d_in[10];
  const float* W1  = (const float*)d_in[11];
  const float* b1  = (const float*)d_in[12];
  const float* W2  = (const float*)d_in[13];
  const float* b2  = (const float*)d_in[14];
  const float* Wa2 = (const float*)d_in[15];
  const float* ba2 = (const float*)d_in[16];
  const float* g2  = (const float*)d_in[17];
  const float* be2 = (const float*)d_in[18];

  char* ws = (char*)d_ws;
  size_t off = 0;
  auto alloc = [&](size_t bytes) -> void* {
    void* p = ws + off;
    off += (bytes + 255) & ~(size_t)255;
    return p;
  };
  unsigned short* xb    = (unsigned short*)alloc((size_t)NTOK*HD*2);
  unsigned short* WqkvT = (unsigned short*)alloc((size_t)3*HD*HD*2);
  unsigned short* Wa1T  = (unsigned short*)alloc((size_t)HD*HD*2);
  unsigned short* W1T   = (unsigned short*)alloc((size_t)FF*HD*2);
  unsigned short* W2T   = (unsigned short*)alloc((size_t)HD*FF*2);
  unsigned short* Wa2T  = (unsigned short*)alloc((size_t)HD*HD*2);
  float*          biasqkv = (float*)alloc((size_t)3*HD*4);
  unsigned short* qkvb  = (unsigned short*)alloc((size_t)NTOK*3*HD*2);
  unsigned short* vtb   = (unsigned short*)alloc((size_t)NTOK*HD*2);
  unsigned short* ctxb  = (unsigned short*)alloc((size_t)NTOK*HD*2);
  unsigned short* a1b   = (unsigned short*)alloc((size_t)NTOK*HD*2);
  unsigned short* an1b  = (unsigned short*)alloc((size_t)NTOK*HD*2);
  unsigned short* h1g   = (unsigned short*)alloc((size_t)NTOK*FF*2);
  unsigned short* f2b   = (unsigned short*)alloc((size_t)NTOK*HD*2);
  unsigned short* a2b   = (unsigned short*)alloc((size_t)NTOK*HD*2);
  (void)ws_size; (void)in_sizes; (void)n_in; (void)out_size;

  k_prep<<<9536, 256, 0, stream>>>(Wq, Wk, Wv, Wa1, W1, W2, Wa2,
                                   WqkvT, Wa1T, W1T, W2T, Wa2T,
                                   x, xb, NTOK*HD/4, bq, bk, bv, biasqkv);

  // qkv = x @ [Wq|Wk|Wv] + bias; Q scaled; V written transposed to vtb
  k_gemm<3,128><<<dim3(NTOK/128, 2304/BN), 256, 0, stream>>>(xb, WqkvT, biasqkv, qkvb, vtb, NTOK, 3*HD, HD);
  // MFMA flash attention (QBLK=128)
  k_attn_mfma<<<dim3(SEQ/128, NHEAD, BATCH), 256, 0, stream>>>(qkvb, vtb, ctxb);
  // a1 = ctx @ Wa1 + ba1 (bf16)
  k_gemm<1,64><<<dim3(NTOK/64, HD/BN), 256, 0, stream>>>(ctxb, Wa1T, ba1, a1b, nullptr, NTOK, HD, HD);
  // an1 = LN(a1)*g1+be1 + x (bf16 out)
  k_ln<0,0><<<NTOK/4, 256, 0, stream>>>(a1b, x, g1, be1, nullptr, an1b);
  // h1 = gelu(an1 @ W1 + b1) (bf16)
  k_gemm<2,128><<<dim3(NTOK/128, FF/BN), 256, 0, stream>>>(an1b, W1T, b1, h1g, nullptr, NTOK, FF, HD);
  // f2 = h1 @ W2 + b2 (bf16)
  k_gemm<1,64><<<dim3(NTOK/64, HD/BN), 256, 0, stream>>>(h1g, W2T, b2, f2b, nullptr, NTOK, HD, FF);
  // a2 = f2 @ Wa2 + ba2 (bf16)
  k_gemm<1,64><<<dim3(NTOK/64, HD/BN), 256, 0, stream>>>(f2b, Wa2T, ba2, a2b, nullptr, NTOK, HD, HD);
  // out = LN(a2)*g2+be2 + an1 (f32)
  k_ln<1,1><<<NTOK/4, 256, 0, stream>>>(a2b, an1b, g2, be2, (float*)d_out, nullptr);
}

// Round 17
// 189.603 us; speedup vs baseline: 1.0750x; 1.0750x over previous
//
#include <hip/hip_runtime.h>
#include <stdint.h>
#include <stddef.h>

// BERT encoder layer, MI355X. Round 17: revert round-16's QBLK=128 regression
// (occupancy 23.9->12.4% killed it) back to round-15 attention (QBLK=64,
// KVB=128, key-split + LDS merge, MFMA ones-row denominator). One delta:
// attention __launch_bounds__(256,4) — 4 x 40KB = 160KB fits exactly,
// raising the residency ceiling to absorb tail imbalance.
#define HD 768
#define FF 3072
#define NHEAD 12
#define DHEAD 64
#define SEQ 2048
#define BATCH 2
#define NTOK (SEQ*BATCH)   // 4096
#define SM_SCALE 0.18033688f   // log2(e)/8

typedef __attribute__((ext_vector_type(8))) __bf16 bf16x8;
typedef __attribute__((ext_vector_type(4))) float f32x4;

__device__ __forceinline__ unsigned short f2bf(float f) {
  unsigned int u = __builtin_bit_cast(unsigned int, f);
  u += 0x7fffu + ((u >> 16) & 1u);
  return (unsigned short)(u >> 16);
}
__device__ __forceinline__ float bf2f(unsigned int s) {
  unsigned int u = s << 16;
  return __builtin_bit_cast(float, u);
}
__device__ __forceinline__ float4 ld4bf(const unsigned short* p) {
  uint2 w = *reinterpret_cast<const uint2*>(p);
  float4 o;
  o.x = bf2f(w.x & 0xffffu); o.y = bf2f(w.x >> 16);
  o.z = bf2f(w.y & 0xffffu); o.w = bf2f(w.y >> 16);
  return o;
}

// async global->LDS, 16B per lane; LDS dest = uniform base + lane*16
__device__ __forceinline__ void gl16(const unsigned short* g, unsigned short* l) {
  __builtin_amdgcn_global_load_lds(
      (const __attribute__((address_space(1))) void*)g,
      (__attribute__((address_space(3))) void*)l,
      16, 0, 0);
}

// ---------------- prep kernel (weight transposes + x cvt + bias concat) ----------------
__global__ void k_prep(const float* __restrict__ Wq, const float* __restrict__ Wk,
                       const float* __restrict__ Wv, const float* __restrict__ Wa1,
                       const float* __restrict__ W1, const float* __restrict__ W2,
                       const float* __restrict__ Wa2,
                       unsigned short* __restrict__ WqkvT, unsigned short* __restrict__ Wa1T,
                       unsigned short* __restrict__ W1T, unsigned short* __restrict__ W2T,
                       unsigned short* __restrict__ Wa2T,
                       const float* __restrict__ x, unsigned short* __restrict__ xb, int n4,
                       const float* __restrict__ bq, const float* __restrict__ bk,
                       const float* __restrict__ bv, float* __restrict__ biasqkv) {
  int t = blockIdx.x;
  int tid = threadIdx.x;
  if (t >= 7488) {
    int tb = t - 7488;
    if (tb < 9) {
      int idx = tb * 256 + tid;
      if (idx < 3*HD) {
        float v = idx < HD ? bq[idx] : idx < 2*HD ? bk[idx-HD] : bv[idx-2*HD];
        biasqkv[idx] = v;
      }
    }
    int i = tb * 256 + tid;
    int stride = 2048 * 256;
    for (; i < n4; i += stride) {
      float4 v = reinterpret_cast<const float4*>(x)[i];
      ushort4 o;
      o.x = f2bf(v.x); o.y = f2bf(v.y); o.z = f2bf(v.z); o.w = f2bf(v.w);
      reinterpret_cast<ushort4*>(xb)[i] = o;
    }
    return;
  }
  __shared__ float tile[32][33];
  const float* in; unsigned short* out; int K, N;
  if (t < 2304)      { int seg = t / 576; t -= seg * 576; K = HD; N = HD;
                       in  = seg==0 ? Wq : seg==1 ? Wk : seg==2 ? Wv : Wa1;
                       out = seg<3 ? WqkvT + seg*HD*HD : Wa1T; }
  else if (t < 4608) { t -= 2304; in = W1;  out = W1T;  K = HD; N = FF; }
  else if (t < 6912) { t -= 4608; in = W2;  out = W2T;  K = FF; N = HD; }
  else               { t -= 6912; in = Wa2; out = Wa2T; K = HD; N = HD; }
  int nt = N / 32;
  int nb = (t % nt) * 32, kb = (t / nt) * 32;
  int tx = tid & 31, ty = tid >> 5;   // 32 x 8
  for (int i = ty; i < 32; i += 8)
    tile[i][tx] = in[(size_t)(kb + i) * N + nb + tx];
  __syncthreads();
  for (int i = ty; i < 32; i += 8)
    out[(size_t)(nb + i) * K + kb + tx] = f2bf(tile[tx][i]);
}

// ---------------- GEMM (BK=64, XOR-chunk swizzle, XCD-swizzled grid) ----------------
// MODE 1: bf16 out; 2: tanh-GELU->bf16; 3: QKV (Q cols * SM_SCALE, V cols -> Vout transposed)

#define BN 128
#define BK 64

template<int MODE, int TBM>
__global__ __launch_bounds__(256, 3)
void k_gemm(const unsigned short* __restrict__ A, const unsigned short* __restrict__ Bt,
            const float* __restrict__ bias, void* __restrict__ Cout,
            unsigned short* __restrict__ Vout,
            int M, int N, int K) {
  constexpr int MR = TBM / 32;
  constexpr int AI = TBM / 32;
  __shared__ unsigned short As[TBM*BK];
  __shared__ unsigned short Bs[BN*BK];
  int tid = threadIdx.x;
  int nwg = gridDim.x * gridDim.y;
  int lin = blockIdx.x + gridDim.x * blockIdx.y;
  int nl = (lin & 7) * (nwg >> 3) + (lin >> 3);
  int bm = (nl % gridDim.x) * TBM;
  int bn = (nl / gridDim.x) * BN;
  int wave = tid >> 6, lane = tid & 63;
  int wm = wave >> 1, wn = wave & 1;
  int wr = wm * (TBM/2);
  int wc = wn * 64;
  int fr = lane & 15;
  int hi = lane >> 4;

  f32x4 acc[MR][4];
#pragma unroll
  for (int m = 0; m < MR; ++m)
#pragma unroll
    for (int n = 0; n < 4; ++n) acc[m][n] = (f32x4){0.f,0.f,0.f,0.f};

  int g8 = lane >> 3;
  int cc = (lane & 7) ^ g8;
  int arow = (TBM/4)*wave + g8;
  int brow = 32*wave + g8;
  const unsigned short* ag = A + (size_t)(bm + arow) * K + cc*8;
  const unsigned short* bg = Bt + (size_t)(bn + brow) * K + cc*8;
  unsigned short* asl = As + (TBM/4)*wave*BK;
  unsigned short* bsl = Bs + 32*wave*BK;

  for (int k0 = 0; k0 < K; k0 += BK) {
#pragma unroll
    for (int i = 0; i < AI; ++i)
      gl16(ag + (size_t)(8*i)*K + k0, asl + (8*i)*BK);
#pragma unroll
    for (int i = 0; i < 4; ++i)
      gl16(bg + (size_t)(8*i)*K + k0, bsl + (8*i)*BK);
    __syncthreads();

    bf16x8 af[MR][2], bf[4][2];
#pragma unroll
    for (int m = 0; m < MR; ++m) {
      int R = wr + m*16 + fr, sw = R & 7;
#pragma unroll
      for (int h2 = 0; h2 < 2; ++h2)
        af[m][h2] = __builtin_bit_cast(bf16x8,
          *reinterpret_cast<const uint4*>(&As[R*BK + ((hi + h2*4) ^ sw)*8]));
    }
#pragma unroll
    for (int n = 0; n < 4; ++n) {
      int R = wc + n*16 + fr, sw = R & 7;
#pragma unroll
      for (int h2 = 0; h2 < 2; ++h2)
        bf[n][h2] = __builtin_bit_cast(bf16x8,
          *reinterpret_cast<const uint4*>(&Bs[R*BK + ((hi + h2*4) ^ sw)*8]));
    }
#pragma unroll
    for (int m = 0; m < MR; ++m)
#pragma unroll
      for (int n = 0; n < 4; ++n) {
        acc[m][n] = __builtin_amdgcn_mfma_f32_16x16x32_bf16(af[m][0], bf[n][0], acc[m][n], 0, 0, 0);
        acc[m][n] = __builtin_amdgcn_mfma_f32_16x16x32_bf16(af[m][1], bf[n][1], acc[m][n], 0, 0, 0);
      }
    __syncthreads();
  }

  int crow0 = (lane >> 4) * 4;
  int ccol = lane & 15;

  if (MODE == 3 && bn >= 2*HD) {
    unsigned short* tb = (wave < 2) ? As + wave*4096 : Bs + (wave-2)*4096;
#pragma unroll
    for (int m = 0; m < MR; ++m)
#pragma unroll
      for (int n = 0; n < 4; ++n)
#pragma unroll
        for (int r = 0; r < 4; ++r) {
          int tl = m*16 + crow0 + r;
          int cl = n*16 + ccol;
          float v = acc[m][n][r] + bias[bn + wc + cl];
          int pt = ((tl>>2)&3)*16 + ((tl>>4)<<2) + (tl&3);
          tb[cl*64 + (((pt>>3) ^ (cl&7))<<3) + (pt&7)] = f2bf(v);
        }
    __syncthreads();
    int tk0 = bm + wr;
    int bb = tk0 >> 11;
    int sb = tk0 & 2047;
    int hh = (bn + wc - 2*HD) >> 6;
    unsigned short* dst = Vout + ((size_t)(bb*NHEAD + hh) * DHEAD) * SEQ + sb;
#pragma unroll
    for (int p = 0; p < 8; ++p) {
      int dr = p*8 + (lane >> 3);
      int cj = lane & 7;
      uint4 w = *reinterpret_cast<const uint4*>(&tb[dr*64 + ((cj ^ (dr&7))<<3)]);
      *reinterpret_cast<uint4*>(dst + (size_t)dr*SEQ + cj*8) = w;
    }
    return;
  }

#pragma unroll
  for (int m = 0; m < MR; ++m) {
#pragma unroll
    for (int n = 0; n < 4; ++n) {
      int gcol = bn + wc + n*16 + ccol;
      float bv_ = bias[gcol];
#pragma unroll
      for (int r = 0; r < 4; ++r) {
        int grow = bm + wr + m*16 + crow0 + r;
        float v = acc[m][n][r] + bv_;
        if (MODE == 2) {
          float a = v + 0.044715f * v * v * v;
          v = v / (1.0f + exp2f(-2.3022082f * a));
        }
        if (MODE == 3 && gcol < HD) v *= SM_SCALE;
        reinterpret_cast<unsigned short*>(Cout)[(size_t)grow * N + gcol] = f2bf(v);
      }
    }
  }
}

// ---------------- MFMA flash attention (round-15 structure) ----------------
// QBLK=64, KVB=128; 2D wave split (qh = q-half 32 rows, kh = key-half 64 keys).
// Denominator via MFMA against ones-row (Vt row 64; rows 65..79 zero).
// Merge buffer Mg overlaps Ks/Vt (dead after the loop).

#define KVB 128
#define KPK 72    // K pitch (shorts)
#define KPV 136   // V pitch (shorts)

__global__ __launch_bounds__(256, 4)
void k_attn_mfma(const unsigned short* __restrict__ qkv,
                 const unsigned short* __restrict__ vt,
                 unsigned short* __restrict__ ctx) {
  __shared__ __align__(16) char smem[40960];
  auto Ks = reinterpret_cast<unsigned short(*)[KPK]>(smem);            // [128][72]  = 18432 B
  auto Vt = reinterpret_cast<unsigned short(*)[KPV]>(smem + 18432);    // [80][136]  = 21760 B
  auto Mg = reinterpret_cast<f32x4(*)[64]>(smem);                      // [2*10][64] = 20480 B (overlap)

  int tid = threadIdx.x;
  int wv = tid >> 6, lane = tid & 63;
  int lo = lane & 15, hi = lane >> 4;
  int qh = wv & 1;
  int kh = wv >> 1;

  // XCD swizzle: bijective remap of 768 blocks (768 = 8*96)
  int lin = blockIdx.x + 32*(blockIdx.y + NHEAD*blockIdx.z);
  int nl = (lin & 7) * 96 + (lin >> 3);
  int qb = nl & 31;
  int rest = nl >> 5;
  int h = rest % NHEAD;
  int b = rest / NHEAD;
  int q0 = qb * 64;

  // ones/zero rows for the denominator MFMA (written once; staging rows < 64)
  for (int idx = tid; idx < 16*KPV; idx += 256) {
    int rr = idx / KPV, cc2 = idx - rr*KPV;
    Vt[64 + rr][cc2] = (rr == 0) ? (unsigned short)0x3F80 : (unsigned short)0;
  }

  const unsigned short* qpA = qkv + (size_t)(b*SEQ + q0 + qh*32 + lo) * 2304 + h*DHEAD + hi*8;
  const unsigned short* qpB = qpA + (size_t)16 * 2304;
  bf16x8 qfA0 = __builtin_bit_cast(bf16x8, *reinterpret_cast<const uint4*>(qpA));
  bf16x8 qfA1 = __builtin_bit_cast(bf16x8, *reinterpret_cast<const uint4*>(qpA + 32));
  bf16x8 qfB0 = __builtin_bit_cast(bf16x8, *reinterpret_cast<const uint4*>(qpB));
  bf16x8 qfB1 = __builtin_bit_cast(bf16x8, *reinterpret_cast<const uint4*>(qpB + 32));

  f32x4 poA[4], poB[4], po5A, po5B;
#pragma unroll
  for (int dt = 0; dt < 4; ++dt) { poA[dt] = (f32x4){0.f,0.f,0.f,0.f}; poB[dt] = (f32x4){0.f,0.f,0.f,0.f}; }
  po5A = (f32x4){0.f,0.f,0.f,0.f};
  po5B = (f32x4){0.f,0.f,0.f,0.f};

  // staging: K 128 rows x 64 shorts (2 threads/row), V 64 rows x 128 shorts (4 threads/row)
  int ksr = tid >> 1, kc = (tid & 1) * 32;
  int vdr = tid >> 2, vc = (tid & 3) * 32;
  const unsigned short* kgl = qkv + (size_t)(b*SEQ)*2304 + HD + h*DHEAD;
  const unsigned short* vgl = vt + ((size_t)(b*NHEAD + h)) * DHEAD * SEQ;

  for (int t0 = 0; t0 < SEQ; t0 += KVB) {
    const unsigned short* kp = kgl + (size_t)(t0 + ksr)*2304 + kc;
    const unsigned short* vp = vgl + (size_t)vdr*SEQ + t0 + vc;
    uint4 ku0 = *reinterpret_cast<const uint4*>(kp);
    uint4 ku1 = *reinterpret_cast<const uint4*>(kp + 8);
    uint4 ku2 = *reinterpret_cast<const uint4*>(kp + 16);
    uint4 ku3 = *reinterpret_cast<const uint4*>(kp + 24);
    uint4 vu0 = *reinterpret_cast<const uint4*>(vp);
    uint4 vu1 = *reinterpret_cast<const uint4*>(vp + 8);
    uint4 vu2 = *reinterpret_cast<const uint4*>(vp + 16);
    uint4 vu3 = *reinterpret_cast<const uint4*>(vp + 24);
    __syncthreads();
    *reinterpret_cast<uint4*>(&Ks[ksr][kc])      = ku0;
    *reinterpret_cast<uint4*>(&Ks[ksr][kc + 8])  = ku1;
    *reinterpret_cast<uint4*>(&Ks[ksr][kc + 16]) = ku2;
    *reinterpret_cast<uint4*>(&Ks[ksr][kc + 24]) = ku3;
    *reinterpret_cast<uint4*>(&Vt[vdr][vc])      = vu0;
    *reinterpret_cast<uint4*>(&Vt[vdr][vc + 8])  = vu1;
    *reinterpret_cast<uint4*>(&Vt[vdr][vc + 16]) = vu2;
    *reinterpret_cast<uint4*>(&Vt[vdr][vc + 24]) = vu3;
    __syncthreads();

    // QK^T: wave's 64 keys (kh*64 ..), kg in 0..3
    f32x4 sA[4], sB[4];
#pragma unroll
    for (int kg = 0; kg < 4; ++kg) {
      int krow = kh*64 + kg*16 + lo;
      bf16x8 a0 = __builtin_bit_cast(bf16x8, *reinterpret_cast<const uint4*>(&Ks[krow][hi*8]));
      bf16x8 a1 = __builtin_bit_cast(bf16x8, *reinterpret_cast<const uint4*>(&Ks[krow][32 + hi*8]));
      f32x4 s = (f32x4){0.f,0.f,0.f,0.f};
      s = __builtin_amdgcn_mfma_f32_16x16x32_bf16(a0, qfA0, s, 0, 0, 0);
      s = __builtin_amdgcn_mfma_f32_16x16x32_bf16(a1, qfA1, s, 0, 0, 0);
      sA[kg] = s;
      s = (f32x4){0.f,0.f,0.f,0.f};
      s = __builtin_amdgcn_mfma_f32_16x16x32_bf16(a0, qfB0, s, 0, 0, 0);
      s = __builtin_amdgcn_mfma_f32_16x16x32_bf16(a1, qfB1, s, 0, 0, 0);
      sB[kg] = s;
    }

    // no-max softmax, cvt_pk packing (denominator via MFMA ones-column)
    unsigned int pwA[8], pwB[8];
#pragma unroll
    for (int kg = 0; kg < 4; ++kg) {
      float a0 = exp2f(sA[kg][0]), a1 = exp2f(sA[kg][1]);
      float a2 = exp2f(sA[kg][2]), a3 = exp2f(sA[kg][3]);
      asm("v_cvt_pk_bf16_f32 %0, %1, %2" : "=v"(pwA[kg*2])   : "v"(a0), "v"(a1));
      asm("v_cvt_pk_bf16_f32 %0, %1, %2" : "=v"(pwA[kg*2+1]) : "v"(a2), "v"(a3));
      float b0 = exp2f(sB[kg][0]), b1 = exp2f(sB[kg][1]);
      float b2 = exp2f(sB[kg][2]), b3 = exp2f(sB[kg][3]);
      asm("v_cvt_pk_bf16_f32 %0, %1, %2" : "=v"(pwB[kg*2])   : "v"(b0), "v"(b1));
      asm("v_cvt_pk_bf16_f32 %0, %1, %2" : "=v"(pwB[kg*2+1]) : "v"(b2), "v"(b3));
    }

    uint4 uA0; uA0.x = pwA[0]; uA0.y = pwA[1]; uA0.z = pwA[2]; uA0.w = pwA[3];
    uint4 uA1; uA1.x = pwA[4]; uA1.y = pwA[5]; uA1.z = pwA[6]; uA1.w = pwA[7];
    uint4 uB0; uB0.x = pwB[0]; uB0.y = pwB[1]; uB0.z = pwB[2]; uB0.w = pwB[3];
    uint4 uB1; uB1.x = pwB[4]; uB1.y = pwB[5]; uB1.z = pwB[6]; uB1.w = pwB[7];
    bf16x8 paA0 = __builtin_bit_cast(bf16x8, uA0);
    bf16x8 paA1 = __builtin_bit_cast(bf16x8, uA1);
    bf16x8 paB0 = __builtin_bit_cast(bf16x8, uB0);
    bf16x8 paB1 = __builtin_bit_cast(bf16x8, uB1);

    // PV (keys kh*64.., permuted storage): slots hi*16+j / +8
#pragma unroll
    for (int dt = 0; dt < 4; ++dt) {
      int col = dt*16 + lo;
      bf16x8 v0 = __builtin_bit_cast(bf16x8, *reinterpret_cast<const uint4*>(&Vt[col][kh*64 + hi*16]));
      bf16x8 v1 = __builtin_bit_cast(bf16x8, *reinterpret_cast<const uint4*>(&Vt[col][kh*64 + hi*16 + 8]));
      poA[dt] = __builtin_amdgcn_mfma_f32_16x16x32_bf16(paA0, v0, poA[dt], 0, 0, 0);
      poA[dt] = __builtin_amdgcn_mfma_f32_16x16x32_bf16(paA1, v1, poA[dt], 0, 0, 0);
      poB[dt] = __builtin_amdgcn_mfma_f32_16x16x32_bf16(paB0, v0, poB[dt], 0, 0, 0);
      poB[dt] = __builtin_amdgcn_mfma_f32_16x16x32_bf16(paB1, v1, poB[dt], 0, 0, 0);
    }
    // denominator: ones-row block (rows 64..79); result col 0 (lanes lo==0)
    {
      bf16x8 o0 = __builtin_bit_cast(bf16x8, *reinterpret_cast<const uint4*>(&Vt[64 + lo][kh*64 + hi*16]));
      bf16x8 o1 = __builtin_bit_cast(bf16x8, *reinterpret_cast<const uint4*>(&Vt[64 + lo][kh*64 + hi*16 + 8]));
      po5A = __builtin_amdgcn_mfma_f32_16x16x32_bf16(paA0, o0, po5A, 0, 0, 0);
      po5A = __builtin_amdgcn_mfma_f32_16x16x32_bf16(paA1, o1, po5A, 0, 0, 0);
      po5B = __builtin_amdgcn_mfma_f32_16x16x32_bf16(paB0, o0, po5B, 0, 0, 0);
      po5B = __builtin_amdgcn_mfma_f32_16x16x32_bf16(paB1, o1, po5B, 0, 0, 0);
    }
  }

  // merge key-halves; Mg overlaps Ks/Vt -> barrier BEFORE writes
  __syncthreads();
  if (kh == 1) {
#pragma unroll
    for (int dt = 0; dt < 4; ++dt) {
      Mg[qh*10 + dt][lane] = poA[dt];
      Mg[qh*10 + 4 + dt][lane] = poB[dt];
    }
    Mg[qh*10 + 8][lane] = po5A;
    Mg[qh*10 + 9][lane] = po5B;
  }
  __syncthreads();
  if (kh == 0) {
#pragma unroll
    for (int dt = 0; dt < 4; ++dt) {
      f32x4 mA = Mg[qh*10 + dt][lane], mB = Mg[qh*10 + 4 + dt][lane];
      poA[dt][0] += mA[0]; poA[dt][1] += mA[1]; poA[dt][2] += mA[2]; poA[dt][3] += mA[3];
      poB[dt][0] += mB[0]; poB[dt][1] += mB[1]; poB[dt][2] += mB[2]; poB[dt][3] += mB[3];
    }
    f32x4 m5A = Mg[qh*10 + 8][lane], m5B = Mg[qh*10 + 9][lane];
    po5A[0] += m5A[0]; po5A[1] += m5A[1]; po5A[2] += m5A[2]; po5A[3] += m5A[3];
    po5B[0] += m5B[0]; po5B[1] += m5B[1]; po5B[2] += m5B[2]; po5B[3] += m5B[3];

    unsigned short* op = ctx + (size_t)(b*SEQ + q0 + qh*32) * HD + h*DHEAD;
#pragma unroll
    for (int r = 0; r < 4; ++r) {
      // denominator for row hi*4+r lives on lane (lo=0, hi) -> lane hi*16
      float LA = __shfl(po5A[r], hi*16);
      float LB = __shfl(po5B[r], hi*16);
      float liA = (LA > 0.f) ? 1.0f / LA : 0.f;
      float liB = (LB > 0.f) ? 1.0f / LB : 0.f;
      int row = hi*4 + r;
#pragma unroll
      for (int dt = 0; dt < 4; ++dt) {
        op[(size_t)row*HD + dt*16 + lo]        = f2bf(poA[dt][r] * liA);
        op[(size_t)(16 + row)*HD + dt*16 + lo] = f2bf(poB[dt][r] * liB);
      }
    }
  }
}

// ---------------- LayerNorm (bf16 input) ----------------
template<int RESID_BF16, int WRITE_F32>
__global__ __launch_bounds__(256, 4)
void k_ln(const unsigned short* __restrict__ xin, const void* __restrict__ resid_,
          const float* __restrict__ g, const float* __restrict__ be,
          float* __restrict__ outf, unsigned short* __restrict__ outb) {
  int wave = threadIdx.x >> 6, lane = threadIdx.x & 63;
  int row = blockIdx.x * 4 + wave;
  const unsigned short* xp = xin + (size_t)row * HD;
  const float4* gp = reinterpret_cast<const float4*>(g);
  const float4* bp = reinterpret_cast<const float4*>(be);
  float4 v[3];
  float sum = 0.f, sq = 0.f;
#pragma unroll
  for (int i = 0; i < 3; ++i) {
    v[i] = ld4bf(xp + (lane + 64*i)*4);
    sum += v[i].x + v[i].y + v[i].z + v[i].w;
    sq  += v[i].x*v[i].x + v[i].y*v[i].y + v[i].z*v[i].z + v[i].w*v[i].w;
  }
#pragma unroll
  for (int m = 1; m < 64; m <<= 1) { sum += __shfl_xor(sum, m); sq += __shfl_xor(sq, m); }
  float mean = sum * (1.0f/768.0f);
  float var = sq * (1.0f/768.0f) - mean*mean;
  float rstd = rsqrtf(var + 1e-5f);
#pragma unroll
  for (int i = 0; i < 3; ++i) {
    float4 gg = gp[lane + 64*i], bb = bp[lane + 64*i];
    float4 rr;
    if (RESID_BF16)
      rr = ld4bf((const unsigned short*)resid_ + (size_t)row * HD + (lane + 64*i)*4);
    else
      rr = reinterpret_cast<const float4*>((const float*)resid_ + (size_t)row * HD)[lane + 64*i];
    float4 o;
    o.x = (v[i].x - mean)*rstd*gg.x + bb.x + rr.x;
    o.y = (v[i].y - mean)*rstd*gg.y + bb.y + rr.y;
    o.z = (v[i].z - mean)*rstd*gg.z + bb.z + rr.z;
    o.w = (v[i].w - mean)*rstd*gg.w + bb.w + rr.w;
    if (WRITE_F32) {
      reinterpret_cast<float4*>(outf + (size_t)row * HD)[lane + 64*i] = o;
    } else {
      ushort4 ob;
      ob.x = f2bf(o.x); ob.y = f2bf(o.y); ob.z = f2bf(o.z); ob.w = f2bf(o.w);
      reinterpret_cast<ushort4*>(outb + (size_t)row * HD)[lane + 64*i] = ob;
    }
  }
}

// ---------------- launch ----------------

extern "C" void kernel_launch(void* const* d_in, const int* in_sizes, int n_in,
                              void* d_out, int out_size, void* d_ws, size_t ws_size,
                              hipStream_t stream) {
  const float* x   = (const float*)d_in[0];
  const float* Wq  = (const float*)d_in[1];
  const float* bq  = (const float*)d_in[2];
  const float* Wk  = (const float*)d_in[3];
  const float* bk  = (const float*)d_in[4];
  const float* Wv  = (const float*)d_in[5];
  const float* bv  = (const float*)d_in[6];
  const float* Wa1 = (const float*)d_in[7];
  const float* ba1 = (const float*)d_in[8];
  const float* g1  = (const float*)d_in[9];
  const float* be1 = (const float*)d_in[10];
  const float* W1  = (const float*)d_in[11];
  const float* b1  = (const float*)d_in[12];
  const float* W2  = (const float*)d_in[13];
  const float* b2  = (const float*)d_in[14];
  const float* Wa2 = (const float*)d_in[15];
  const float* ba2 = (const float*)d_in[16];
  const float* g2  = (const float*)d_in[17];
  const float* be2 = (const float*)d_in[18];

  char* ws = (char*)d_ws;
  size_t off = 0;
  auto alloc = [&](size_t bytes) -> void* {
    void* p = ws + off;
    off += (bytes + 255) & ~(size_t)255;
    return p;
  };
  unsigned short* xb    = (unsigned short*)alloc((size_t)NTOK*HD*2);
  unsigned short* WqkvT = (unsigned short*)alloc((size_t)3*HD*HD*2);
  unsigned short* Wa1T  = (unsigned short*)alloc((size_t)HD*HD*2);
  unsigned short* W1T   = (unsigned short*)alloc((size_t)FF*HD*2);
  unsigned short* W2T   = (unsigned short*)alloc((size_t)HD*FF*2);
  unsigned short* Wa2T  = (unsigned short*)alloc((size_t)HD*HD*2);
  float*          biasqkv = (float*)alloc((size_t)3*HD*4);
  unsigned short* qkvb  = (unsigned short*)alloc((size_t)NTOK*3*HD*2);
  unsigned short* vtb   = (unsigned short*)alloc((size_t)NTOK*HD*2);
  unsigned short* ctxb  = (unsigned short*)alloc((size_t)NTOK*HD*2);
  unsigned short* a1b   = (unsigned short*)alloc((size_t)NTOK*HD*2);
  unsigned short* an1b  = (unsigned short*)alloc((size_t)NTOK*HD*2);
  unsigned short* h1g   = (unsigned short*)alloc((size_t)NTOK*FF*2);
  unsigned short* f2b   = (unsigned short*)alloc((size_t)NTOK*HD*2);
  unsigned short* a2b   = (unsigned short*)alloc((size_t)NTOK*HD*2);
  (void)ws_size; (void)in_sizes; (void)n_in; (void)out_size;

  k_prep<<<9536, 256, 0, stream>>>(Wq, Wk, Wv, Wa1, W1, W2, Wa2,
                                   WqkvT, Wa1T, W1T, W2T, Wa2T,
                                   x, xb, NTOK*HD/4, bq, bk, bv, biasqkv);

  // qkv = x @ [Wq|Wk|Wv] + bias; Q scaled; V written transposed to vtb
  k_gemm<3,128><<<dim3(NTOK/128, 2304/BN), 256, 0, stream>>>(xb, WqkvT, biasqkv, qkvb, vtb, NTOK, 3*HD, HD);
  // MFMA flash attention (QBLK=64)
  k_attn_mfma<<<dim3(SEQ/64, NHEAD, BATCH), 256, 0, stream>>>(qkvb, vtb, ctxb);
  // a1 = ctx @ Wa1 + ba1 (bf16)
  k_gemm<1,64><<<dim3(NTOK/64, HD/BN), 256, 0, stream>>>(ctxb, Wa1T, ba1, a1b, nullptr, NTOK, HD, HD);
  // an1 = LN(a1)*g1+be1 + x (bf16 out)
  k_ln<0,0><<<NTOK/4, 256, 0, stream>>>(a1b, x, g1, be1, nullptr, an1b);
  // h1 = gelu(an1 @ W1 + b1) (bf16)
  k_gemm<2,128><<<dim3(NTOK/128, FF/BN), 256, 0, stream>>>(an1b, W1T, b1, h1g, nullptr, NTOK, FF, HD);
  // f2 = h1 @ W2 + b2 (bf16)
  k_gemm<1,64><<<dim3(NTOK/64, HD/BN), 256, 0, stream>>>(h1g, W2T, b2, f2b, nullptr, NTOK, HD, FF);
  // a2 = f2 @ Wa2 + ba2 (bf16)
  k_gemm<1,64><<<dim3(NTOK/64, HD/BN), 256, 0, stream>>>(f2b, Wa2T, ba2, a2b, nullptr, NTOK, HD, HD);
  // out = LN(a2)*g2+be2 + an1 (f32)
  k_ln<1,1><<<NTOK/4, 256, 0, stream>>>(a2b, an1b, g2, be2, (float*)d_out, nullptr);
}